// Round 8
// baseline (161.689 us; speedup 1.0000x reference)
//
#include <hip/hip_runtime.h>
#include <hip/hip_bf16.h>
#include <math.h>

#define BATCH 4
#define SEQ   4096
#define DIM   256
#define AS1 __attribute__((address_space(1)))
#define AS3 __attribute__((address_space(3)))

typedef __attribute__((ext_vector_type(8))) short  bf16x8;
typedef __attribute__((ext_vector_type(4))) short  bf16x4;
typedef __attribute__((ext_vector_type(4))) float  f32x4;
typedef __attribute__((ext_vector_type(4))) int    i32x4;

__device__ __forceinline__ short f2bf(float f) {
    union { float f; unsigned u; } v; v.f = f;
    unsigned r = (v.u + 0x7fffu + ((v.u >> 16) & 1u)) >> 16;
    return (short)r;
}

__device__ __forceinline__ void gload_lds16(const void* g, void* l) {
    __builtin_amdgcn_global_load_lds((const AS1 void*)g, (AS3 void*)l, 16, 0, 0);
}

// ---------------------------------------------------------------------------
// Projection: out[n][e] = (sum_d A[n][d]*W[e][d] + bias[e]) * scale  (bf16)
// TRANS=true stores out^T per batch ([b][256][4096]).
// ---------------------------------------------------------------------------
template<bool TRANS>
__global__ __launch_bounds__(256) void proj_kernel(
    const float* __restrict__ A,
    const float* __restrict__ W,
    const float* __restrict__ bias,
    unsigned short* __restrict__ out,
    float scale)
{
    __shared__ __align__(16) short Wlds[256 * 40];

    const int t    = threadIdx.x;
    const int wave = t >> 6, lane = t & 63;
    const int c    = lane & 15, g = lane >> 4;
    const int wrow = blockIdx.x * 64 + wave * 16;

    f32x4 acc[16];
    for (int nt = 0; nt < 16; ++nt) acc[nt] = f32x4{0.f, 0.f, 0.f, 0.f};

    f32x4 wpf[8];
    for (int i = 0; i < 8; ++i) {
        int f = i * 1024 + t * 4;
        wpf[i] = *(const f32x4*)&W[(f >> 5) * 256 + (f & 31)];
    }
    f32x4 a0 = *(const f32x4*)&A[(wrow + c) * 256 + g * 8];
    f32x4 a1 = *(const f32x4*)&A[(wrow + c) * 256 + g * 8 + 4];

    for (int ks = 0; ks < 8; ++ks) {
        __syncthreads();
        for (int i = 0; i < 8; ++i) {
            int f = i * 1024 + t * 4;
            bf16x4 s4;
            s4[0] = f2bf(wpf[i][0]); s4[1] = f2bf(wpf[i][1]);
            s4[2] = f2bf(wpf[i][2]); s4[3] = f2bf(wpf[i][3]);
            *(bf16x4*)&Wlds[(f >> 5) * 40 + (f & 31)] = s4;
        }
        __syncthreads();
        bf16x8 af;
        af[0] = f2bf(a0[0]); af[1] = f2bf(a0[1]); af[2] = f2bf(a0[2]); af[3] = f2bf(a0[3]);
        af[4] = f2bf(a1[0]); af[5] = f2bf(a1[1]); af[6] = f2bf(a1[2]); af[7] = f2bf(a1[3]);
        if (ks < 7) {
            for (int i = 0; i < 8; ++i) {
                int f = i * 1024 + t * 4;
                wpf[i] = *(const f32x4*)&W[(f >> 5) * 256 + (ks + 1) * 32 + (f & 31)];
            }
            a0 = *(const f32x4*)&A[(wrow + c) * 256 + (ks + 1) * 32 + g * 8];
            a1 = *(const f32x4*)&A[(wrow + c) * 256 + (ks + 1) * 32 + g * 8 + 4];
        }
        __builtin_amdgcn_s_setprio(1);
        for (int nt = 0; nt < 16; ++nt) {
            bf16x8 bfr = *(const bf16x8*)&Wlds[(nt * 16 + c) * 40 + g * 8];
            acc[nt] = __builtin_amdgcn_mfma_f32_16x16x32_bf16(af, bfr, acc[nt], 0, 0, 0);
        }
        __builtin_amdgcn_s_setprio(0);
    }

    if constexpr (TRANS) {
        const int nb = wrow >> 12, n0 = wrow & 4095;
        for (int nt = 0; nt < 16; ++nt) {
            float bv = bias[nt * 16 + c];
            bf16x4 s4;
            s4[0] = f2bf((acc[nt][0] + bv) * scale); s4[1] = f2bf((acc[nt][1] + bv) * scale);
            s4[2] = f2bf((acc[nt][2] + bv) * scale); s4[3] = f2bf((acc[nt][3] + bv) * scale);
            *(bf16x4*)&out[((size_t)nb * DIM + nt * 16 + c) * SEQ + n0 + g * 4] = s4;
        }
    } else {
        for (int nt = 0; nt < 16; ++nt) {
            float bv = bias[nt * 16 + c];
            for (int j = 0; j < 4; ++j)
                out[(size_t)(wrow + g * 4 + j) * 256 + nt * 16 + c] =
                    (unsigned short)f2bf((acc[nt][j] + bv) * scale);
        }
    }
}

// ---------------------------------------------------------------------------
// Flash attention, hybrid layout + K-row permutation (P stays in registers).
// 8 waves x 16 q-rows = 128 q-rows/block, KVB=32, gload_lds dbuf staging.
// QK swapped with A-rows permuted: A-row r <- K row phi(r)=(r&3)+8*(r>>2)
// (s0) and phi(r)+4 (s1). Then lane (c,g) holds S[q=c][k=8g+0..3] in s0 and
// S[q=c][k=8g+4..7] in s1 == exactly the PV A-fragment k-slots. P is packed
// in-lane (8 cvt + pack) -> NO LDS roundtrip, NO shuffles steady-state.
// K stage pre-swizzle sigma_c(kr)=(kr&3)|((kr&8)>>1); read XOR stays (c&7)<<3
// because sigma_c(phi(c)) = sigma_c(phi(c)+4) = c&7.
// PV normal: O = mfma(pa, vf). Q pre-scaled by 1/sqrt(D).
// ---------------------------------------------------------------------------
#define KVB 32

__global__ __launch_bounds__(512, 4) void fa2_kernel(
    const unsigned short* __restrict__ Q,   // [4][4096][256] bf16 (pre-scaled)
    const unsigned short* __restrict__ K,   // [4][4096][256] bf16
    const unsigned short* __restrict__ Vt,  // [4][256][4096] bf16
    float* __restrict__ Opart,              // [nsplit][4][4096][256] f32 (l-normalized)
    float2* __restrict__ ml,                // [nsplit][4*4096]
    int nsplit)
{
    __shared__ __align__(16) unsigned short Klds[2][KVB * 256];   // 2 x 16 KB
    __shared__ __align__(16) unsigned short Vlds[2][256 * KVB];   // 2 x 16 KB

    const int t = threadIdx.x;
    const int w = t >> 6, lane = t & 63;
    const int c = lane & 15, g = lane >> 4;

    int b, sidx, qt;
    if (nsplit == 4) {
        int xcd  = blockIdx.x & 7;
        int rest = blockIdx.x >> 3;            // 0..63
        int combo = (xcd << 1) | (rest >> 5);  // 0..15 ; 2 combos per XCD
        qt   = rest & 31;
        b    = combo >> 2;
        sidx = combo & 3;
    } else {
        qt   = blockIdx.x & 31;
        b    = blockIdx.x >> 5;
        sidx = 0;
    }
    const int ts = (sidx * 128) / nsplit;
    const int te = ((sidx + 1) * 128) / nsplit;

    const int wrow = qt * 128 + w * 16;   // wave's 16 q-rows; this lane owns q = wrow+c

    // Q fragments: lane holds Q[wrow+c][ks*32 + g*8 .. +7]
    bf16x8 qf[8];
    const unsigned short* Qrow = &Q[((size_t)b * SEQ + wrow + c) * DIM];
    #pragma unroll
    for (int ks = 0; ks < 8; ++ks)
        qf[ks] = *(const bf16x8*)&Qrow[ks * 32 + g * 8];

    // O accumulators (normal layout): o[nt][j] = O[q=wrow+4g+j][d=16nt+c]
    f32x4 o[16];
    #pragma unroll
    for (int nt = 0; nt < 16; ++nt) o[nt] = f32x4{0.f, 0.f, 0.f, 0.f};
    float m = -1e30f, llane = 0.f;   // state for q = wrow+c (this lane's k-subset)

    const char* Kb_ = (const char*)&K[(size_t)b * SEQ * DIM];
    const char* Vb_ = (const char*)&Vt[(size_t)b * DIM * SEQ];

    // Staging: 16 x 1KB DMA calls per tile each for K and V; wave w does 2 of each.
    const int l31   = lane & 31;
    const int krow0 = 4 * w + (lane >> 5);
    const int krow1 = krow0 + 2;
    const int sc0   = (krow0 & 3) | ((krow0 & 8) >> 1);   // sigma_c
    const int sc1   = (krow1 & 3) | ((krow1 & 8) >> 1);
    const int koff0 = krow0 * 512 + ((l31 ^ sc0) << 4);
    const int koff1 = krow1 * 512 + ((l31 ^ sc1) << 4);
    const int vrow0 = 32 * w + (lane >> 2);
    const int vrow1 = vrow0 + 16;
    const int vsw0  = ((vrow0 & 3) ^ ((vrow0 >> 2) & 3));
    const int vsw1  = ((vrow1 & 3) ^ ((vrow1 >> 2) & 3));
    const int voff0 = vrow0 * (SEQ * 2) + (((lane & 3) ^ vsw0) << 4);
    const int voff1 = vrow1 * (SEQ * 2) + (((lane & 3) ^ vsw1) << 4);

    #define STAGE(kt_, buf_) do {                                              \
        const size_t kb_ = (size_t)(kt_) * (KVB * DIM * 2);                    \
        const size_t vb_ = (size_t)(kt_) * (KVB * 2);                          \
        gload_lds16(Kb_ + kb_ + koff0, &Klds[buf_][(2 * w)     * 512]);        \
        gload_lds16(Kb_ + kb_ + koff1, &Klds[buf_][(2 * w + 1) * 512]);        \
        gload_lds16(Vb_ + vb_ + voff0, &Vlds[buf_][(2 * w)     * 512]);        \
        gload_lds16(Vb_ + vb_ + voff1, &Vlds[buf_][(2 * w + 1) * 512]);        \
    } while (0)

    STAGE(ts, 0);
    int buf = 0;

    const int xk   = (c & 7) << 3;                                   // K read swizzle
    const int rphi = ((c & 3) + 8 * (c >> 2));                       // phi(c)
    const int vcol = (g * 8) ^ ((((c & 3) ^ ((c >> 2) & 3))) << 3);  // V read swizzle

    for (int kt = ts; kt < te; ++kt) {
        __builtin_amdgcn_s_barrier();   // all waves done reading buf^1
        if (kt + 1 < te) {
            STAGE(kt + 1, buf ^ 1);
            asm volatile("s_waitcnt vmcnt(4)" ::: "memory");  // tile kt landed
        } else {
            asm volatile("s_waitcnt vmcnt(0)" ::: "memory");
        }
        __builtin_amdgcn_s_barrier();   // tile kt visible to all waves

        const unsigned short* Kl = &Klds[buf][0];
        const unsigned short* Vl = &Vlds[buf][0];

        // S^T with permuted A-rows: s0[j]=S[q=wrow+c][k=8g+j], s1[j]=[k=8g+4+j]
        f32x4 s0 = f32x4{0.f, 0.f, 0.f, 0.f};
        f32x4 s1 = f32x4{0.f, 0.f, 0.f, 0.f};
        __builtin_amdgcn_s_setprio(1);
        #pragma unroll
        for (int ks = 0; ks < 8; ++ks) {
            int off = (ks * 32 + g * 8) ^ xk;
            bf16x8 kf0 = *(const bf16x8*)&Kl[rphi * 256 + off];
            s0 = __builtin_amdgcn_mfma_f32_16x16x32_bf16(kf0, qf[ks], s0, 0, 0, 0);
            bf16x8 kf1 = *(const bf16x8*)&Kl[(rphi + 4) * 256 + off];
            s1 = __builtin_amdgcn_mfma_f32_16x16x32_bf16(kf1, qf[ks], s1, 0, 0, 0);
        }
        __builtin_amdgcn_s_setprio(0);

        // lane-local defer-max softmax (all 8 values belong to q = wrow+c)
        float pm = fmaxf(fmaxf(fmaxf(s0[0], s0[1]), fmaxf(s0[2], s0[3])),
                         fmaxf(fmaxf(s1[0], s1[1]), fmaxf(s1[2], s1[3])));
        if (!__all(pm <= m + 8.f)) {
            pm = fmaxf(pm, __shfl_xor(pm, 16));
            pm = fmaxf(pm, __shfl_xor(pm, 32));   // true row max across g-lanes
            float mn = fmaxf(m, pm);
            float r  = __expf(m - mn);
            m = mn; llane *= r;
            float r0 = __shfl(r, g * 4 + 0), r1 = __shfl(r, g * 4 + 1);
            float r2 = __shfl(r, g * 4 + 2), r3 = __shfl(r, g * 4 + 3);
            #pragma unroll
            for (int nt = 0; nt < 16; ++nt) {
                o[nt][0] *= r0; o[nt][1] *= r1; o[nt][2] *= r2; o[nt][3] *= r3;
            }
        }
        bf16x8 pa;
        {
            float p0 = __expf(s0[0] - m), p1 = __expf(s0[1] - m);
            float p2 = __expf(s0[2] - m), p3 = __expf(s0[3] - m);
            float p4 = __expf(s1[0] - m), p5 = __expf(s1[1] - m);
            float p6 = __expf(s1[2] - m), p7 = __expf(s1[3] - m);
            llane += ((p0 + p1) + (p2 + p3)) + ((p4 + p5) + (p6 + p7));
            pa[0] = f2bf(p0); pa[1] = f2bf(p1); pa[2] = f2bf(p2); pa[3] = f2bf(p3);
            pa[4] = f2bf(p4); pa[5] = f2bf(p5); pa[6] = f2bf(p6); pa[7] = f2bf(p7);
        }

        // PV: O[16][256] += P[16][32] @ V[32][256]  (A-frag built in-lane)
        __builtin_amdgcn_s_setprio(1);
        #pragma unroll
        for (int nt = 0; nt < 16; ++nt) {
            bf16x8 vf = *(const bf16x8*)&Vl[(nt * 16 + c) * 32 + vcol];
            o[nt] = __builtin_amdgcn_mfma_f32_16x16x32_bf16(pa, vf, o[nt], 0, 0, 0);
        }
        __builtin_amdgcn_s_setprio(0);
        buf ^= 1;
    }

    // epilogue: reduce l across g-lanes (same q), broadcast per output row, store
    float lsum = llane;
    lsum += __shfl_xor(lsum, 16);
    lsum += __shfl_xor(lsum, 32);
    float inv = 1.0f / lsum;
    float i0 = __shfl(inv, g * 4 + 0), i1 = __shfl(inv, g * 4 + 1);
    float i2 = __shfl(inv, g * 4 + 2), i3 = __shfl(inv, g * 4 + 3);

    const size_t obase = ((size_t)sidx * BATCH * SEQ + (size_t)b * SEQ + wrow) * DIM;
    for (int nt = 0; nt < 16; ++nt) {
        Opart[obase + (size_t)(g * 4 + 0) * DIM + nt * 16 + c] = o[nt][0] * i0;
        Opart[obase + (size_t)(g * 4 + 1) * DIM + nt * 16 + c] = o[nt][1] * i1;
        Opart[obase + (size_t)(g * 4 + 2) * DIM + nt * 16 + c] = o[nt][2] * i2;
        Opart[obase + (size_t)(g * 4 + 3) * DIM + nt * 16 + c] = o[nt][3] * i3;
    }
    if (g == 0) {
        ml[(size_t)sidx * BATCH * SEQ + (size_t)b * SEQ + wrow + c] =
            make_float2(m, lsum);
    }
}

// ---------------------------------------------------------------------------
// Combine 4 KV-split partials: O = sum_s w_s * O_s, w_s = l_s exp(m_s - M)/L
// ---------------------------------------------------------------------------
__global__ __launch_bounds__(256) void combine_kernel(
    const float* __restrict__ Opart, const float2* __restrict__ ml,
    float* __restrict__ out)
{
    const int t = threadIdx.x;
    const size_t row = (size_t)blockIdx.x * 4 + (t >> 6);
    const int lane = t & 63;

    float2 e[4];
    float M = -1e30f;
    for (int s = 0; s < 4; ++s) {
        e[s] = ml[(size_t)s * BATCH * SEQ + row];
        M = fmaxf(M, e[s].x);
    }
    float wgt[4], L = 0.f;
    for (int s = 0; s < 4; ++s) { wgt[s] = e[s].y * __expf(e[s].x - M); L += wgt[s]; }
    float invL = 1.0f / L;

    f32x4 acc = f32x4{0.f, 0.f, 0.f, 0.f};
    for (int s = 0; s < 4; ++s) {
        f32x4 v = *(const f32x4*)&Opart[((size_t)s * BATCH * SEQ + row) * DIM + lane * 4];
        float ws = wgt[s] * invL;
        acc[0] += ws * v[0]; acc[1] += ws * v[1];
        acc[2] += ws * v[2]; acc[3] += ws * v[3];
    }
    *(f32x4*)&out[row * DIM + lane * 4] = acc;
}

// ---------------------------------------------------------------------------
extern "C" void kernel_launch(void* const* d_in, const int* in_sizes, int n_in,
                              void* d_out, int out_size, void* d_ws, size_t ws_size,
                              hipStream_t stream) {
    const float* x  = (const float*)d_in[0];
    const float* z  = (const float*)d_in[1];
    const float* Wq = (const float*)d_in[2];
    const float* bq = (const float*)d_in[3];
    const float* Wk = (const float*)d_in[4];
    const float* bk = (const float*)d_in[5];
    const float* Wv = (const float*)d_in[6];
    const float* bv = (const float*)d_in[7];
    float* out = (float*)d_out;

    const size_t TENS = (size_t)BATCH * SEQ * DIM;
    unsigned short* Qb  = (unsigned short*)d_ws;
    unsigned short* Kb  = Qb + TENS;
    unsigned short* Vtb = Kb + TENS;

    const size_t base_bytes = 3 * TENS * sizeof(unsigned short);       // 24 MB
    const size_t need4 = base_bytes + 4 * TENS * sizeof(float)         // 64 MB
                       + 4 * (size_t)BATCH * SEQ * sizeof(float2);
    const int nsplit = (ws_size >= need4) ? 4 : 1;

    proj_kernel<false><<<256, 256, 0, stream>>>(x, Wq, bq, Qb, 0.0625f);
    proj_kernel<false><<<256, 256, 0, stream>>>(z, Wk, bk, Kb, 1.0f);
    proj_kernel<true ><<<256, 256, 0, stream>>>(z, Wv, bv, Vtb, 1.0f);

    if (nsplit == 4) {
        float*  Op  = (float*)((char*)d_ws + base_bytes);
        float2* mlb = (float2*)((char*)d_ws + base_bytes + 4 * TENS * sizeof(float));
        fa2_kernel<<<512, 512, 0, stream>>>(Qb, Kb, Vtb, Op, mlb, 4);
        combine_kernel<<<4096, 256, 0, stream>>>(Op, mlb, out);
    } else {
        float2* mlb = (float2*)((char*)d_ws + base_bytes);
        fa2_kernel<<<128, 512, 0, stream>>>(Qb, Kb, Vtb, out, mlb, 1);
    }
}

// Round 9
// 152.053 us; speedup vs baseline: 1.0634x; 1.0634x over previous
//
#include <hip/hip_runtime.h>
#include <hip/hip_bf16.h>
#include <math.h>

#define BATCH 4
#define SEQ   4096
#define DIM   256
#define AS1 __attribute__((address_space(1)))
#define AS3 __attribute__((address_space(3)))

typedef __attribute__((ext_vector_type(8))) short  bf16x8;
typedef __attribute__((ext_vector_type(4))) short  bf16x4;
typedef __attribute__((ext_vector_type(4))) float  f32x4;
typedef __attribute__((ext_vector_type(4))) int    i32x4;

__device__ __forceinline__ short f2bf(float f) {
    union { float f; unsigned u; } v; v.f = f;
    unsigned r = (v.u + 0x7fffu + ((v.u >> 16) & 1u)) >> 16;
    return (short)r;
}

__device__ __forceinline__ void gload_lds16(const void* g, void* l) {
    __builtin_amdgcn_global_load_lds((const AS1 void*)g, (AS3 void*)l, 16, 0, 0);
}

// ---------------------------------------------------------------------------
// Projection: out[n][e] = (sum_d A[n][d]*W[e][d] + bias[e]) * scale  (bf16)
// TRANS=true stores out^T per batch ([b][256][4096]).
// ---------------------------------------------------------------------------
template<bool TRANS>
__global__ __launch_bounds__(256) void proj_kernel(
    const float* __restrict__ A,
    const float* __restrict__ W,
    const float* __restrict__ bias,
    unsigned short* __restrict__ out,
    float scale)
{
    __shared__ __align__(16) short Wlds[256 * 40];

    const int t    = threadIdx.x;
    const int wave = t >> 6, lane = t & 63;
    const int c    = lane & 15, g = lane >> 4;
    const int wrow = blockIdx.x * 64 + wave * 16;

    f32x4 acc[16];
    for (int nt = 0; nt < 16; ++nt) acc[nt] = f32x4{0.f, 0.f, 0.f, 0.f};

    f32x4 wpf[8];
    for (int i = 0; i < 8; ++i) {
        int f = i * 1024 + t * 4;
        wpf[i] = *(const f32x4*)&W[(f >> 5) * 256 + (f & 31)];
    }
    f32x4 a0 = *(const f32x4*)&A[(wrow + c) * 256 + g * 8];
    f32x4 a1 = *(const f32x4*)&A[(wrow + c) * 256 + g * 8 + 4];

    for (int ks = 0; ks < 8; ++ks) {
        __syncthreads();
        for (int i = 0; i < 8; ++i) {
            int f = i * 1024 + t * 4;
            bf16x4 s4;
            s4[0] = f2bf(wpf[i][0]); s4[1] = f2bf(wpf[i][1]);
            s4[2] = f2bf(wpf[i][2]); s4[3] = f2bf(wpf[i][3]);
            *(bf16x4*)&Wlds[(f >> 5) * 40 + (f & 31)] = s4;
        }
        __syncthreads();
        bf16x8 af;
        af[0] = f2bf(a0[0]); af[1] = f2bf(a0[1]); af[2] = f2bf(a0[2]); af[3] = f2bf(a0[3]);
        af[4] = f2bf(a1[0]); af[5] = f2bf(a1[1]); af[6] = f2bf(a1[2]); af[7] = f2bf(a1[3]);
        if (ks < 7) {
            for (int i = 0; i < 8; ++i) {
                int f = i * 1024 + t * 4;
                wpf[i] = *(const f32x4*)&W[(f >> 5) * 256 + (ks + 1) * 32 + (f & 31)];
            }
            a0 = *(const f32x4*)&A[(wrow + c) * 256 + (ks + 1) * 32 + g * 8];
            a1 = *(const f32x4*)&A[(wrow + c) * 256 + (ks + 1) * 32 + g * 8 + 4];
        }
        __builtin_amdgcn_s_setprio(1);
        for (int nt = 0; nt < 16; ++nt) {
            bf16x8 bfr = *(const bf16x8*)&Wlds[(nt * 16 + c) * 40 + g * 8];
            acc[nt] = __builtin_amdgcn_mfma_f32_16x16x32_bf16(af, bfr, acc[nt], 0, 0, 0);
        }
        __builtin_amdgcn_s_setprio(0);
    }

    if constexpr (TRANS) {
        const int nb = wrow >> 12, n0 = wrow & 4095;
        for (int nt = 0; nt < 16; ++nt) {
            float bv = bias[nt * 16 + c];
            bf16x4 s4;
            s4[0] = f2bf((acc[nt][0] + bv) * scale); s4[1] = f2bf((acc[nt][1] + bv) * scale);
            s4[2] = f2bf((acc[nt][2] + bv) * scale); s4[3] = f2bf((acc[nt][3] + bv) * scale);
            *(bf16x4*)&out[((size_t)nb * DIM + nt * 16 + c) * SEQ + n0 + g * 4] = s4;
        }
    } else {
        for (int nt = 0; nt < 16; ++nt) {
            float bv = bias[nt * 16 + c];
            for (int j = 0; j < 4; ++j)
                out[(size_t)(wrow + g * 4 + j) * 256 + nt * 16 + c] =
                    (unsigned short)f2bf((acc[nt][j] + bv) * scale);
        }
    }
}

// ---------------------------------------------------------------------------
// Flash attention: 4 waves x 32 q-rows (2 q-tiles/wave) = 128 q-rows/block.
// KVB=32, gload_lds dbuf staging, vmcnt(8). Every kf/vf LDS read feeds TWO
// MFMAs (q-tile h=0,1) -> MFMA:ds_read = 2:1 (R8 was LDS-port-bound at 1:1).
// QK swapped + K-row permutation phi(r)=(r&3)+8*(r>>2): lane (c,g) gets
// S[q=wrow+16h+c][k=8g+0..7] in s[h] -> lane-local softmax, P in registers.
// K stage pre-swizzle sigma_c(kr)=(kr&3)|((kr&8)>>1); read XOR (c&7)<<3.
// PV normal: O = mfma(pa[h], vf). Q pre-scaled by 1/sqrt(D).
// ---------------------------------------------------------------------------
#define KVB 32

__global__ __launch_bounds__(256, 2) void fa2_kernel(
    const unsigned short* __restrict__ Q,   // [4][4096][256] bf16 (pre-scaled)
    const unsigned short* __restrict__ K,   // [4][4096][256] bf16
    const unsigned short* __restrict__ Vt,  // [4][256][4096] bf16
    float* __restrict__ Opart,              // [nsplit][4][4096][256] f32 (l-normalized)
    float2* __restrict__ ml,                // [nsplit][4*4096]
    int nsplit)
{
    __shared__ __align__(16) unsigned short Klds[2][KVB * 256];   // 2 x 16 KB
    __shared__ __align__(16) unsigned short Vlds[2][256 * KVB];   // 2 x 16 KB

    const int t = threadIdx.x;
    const int w = t >> 6, lane = t & 63;
    const int c = lane & 15, g = lane >> 4;

    int b, sidx, qt;
    if (nsplit == 4) {
        int xcd  = blockIdx.x & 7;
        int rest = blockIdx.x >> 3;            // 0..63
        int combo = (xcd << 1) | (rest >> 5);  // 0..15 ; 2 combos per XCD
        qt   = rest & 31;
        b    = combo >> 2;
        sidx = combo & 3;
    } else {
        qt   = blockIdx.x & 31;
        b    = blockIdx.x >> 5;
        sidx = 0;
    }
    const int ts = (sidx * 128) / nsplit;
    const int te = ((sidx + 1) * 128) / nsplit;

    const int wrow = qt * 128 + w * 32;   // wave's 32 q-rows (2 tiles of 16)

    // Q fragments: qf[h][ks] -> lane holds Q[wrow+16h+c][ks*32 + g*8 .. +7]
    bf16x8 qf[2][8];
    #pragma unroll
    for (int h = 0; h < 2; ++h) {
        const unsigned short* Qrow = &Q[((size_t)b * SEQ + wrow + 16 * h + c) * DIM];
        #pragma unroll
        for (int ks = 0; ks < 8; ++ks)
            qf[h][ks] = *(const bf16x8*)&Qrow[ks * 32 + g * 8];
    }

    // O accumulators: o[h][nt][j] = O[q=wrow+16h+4g+j][d=16nt+c]
    f32x4 o[2][16];
    #pragma unroll
    for (int h = 0; h < 2; ++h)
        #pragma unroll
        for (int nt = 0; nt < 16; ++nt) o[h][nt] = f32x4{0.f, 0.f, 0.f, 0.f};
    float m[2]     = {-1e30f, -1e30f};
    float llane[2] = {0.f, 0.f};

    const char* Kb_ = (const char*)&K[(size_t)b * SEQ * DIM];
    const char* Vb_ = (const char*)&Vt[(size_t)b * DIM * SEQ];

    // Staging: 16 x 1KB DMA calls per tile each for K and V; wave does 4 of each.
    const int l31 = lane & 31;
    int koff[4], voff[4], dstb[4];
    const int vsw = ((lane >> 2) & 3) ^ ((lane >> 4) & 3);
    const int vcb = ((lane & 3) ^ vsw) << 4;
    #pragma unroll
    for (int ii = 0; ii < 4; ++ii) {
        int kr = 8 * w + 2 * ii + (lane >> 5);
        int sc = (kr & 3) | ((kr & 8) >> 1);              // sigma_c
        koff[ii] = kr * 512 + ((l31 ^ sc) << 4);
        int vr = 64 * w + 16 * ii + (lane >> 2);
        voff[ii] = vr * (SEQ * 2) + vcb;
        dstb[ii] = (4 * w + ii) * 1024;
    }

    #define STAGE(kt_, buf_) do {                                              \
        const size_t kb_ = (size_t)(kt_) * (KVB * DIM * 2);                    \
        const size_t vb_ = (size_t)(kt_) * (KVB * 2);                          \
        _Pragma("unroll")                                                      \
        for (int ii = 0; ii < 4; ++ii) {                                       \
            gload_lds16(Kb_ + kb_ + koff[ii], (char*)&Klds[buf_][0] + dstb[ii]); \
            gload_lds16(Vb_ + vb_ + voff[ii], (char*)&Vlds[buf_][0] + dstb[ii]); \
        }                                                                      \
    } while (0)

    STAGE(ts, 0);
    int buf = 0;

    const int xk   = (c & 7) << 3;                                   // K read swizzle
    const int rphi = ((c & 3) + 8 * (c >> 2));                       // phi(c)
    const int vcol = (g * 8) ^ ((((c & 3) ^ ((c >> 2) & 3))) << 3);  // V read swizzle

    for (int kt = ts; kt < te; ++kt) {
        __builtin_amdgcn_s_barrier();   // all waves done reading buf^1
        if (kt + 1 < te) {
            STAGE(kt + 1, buf ^ 1);
            asm volatile("s_waitcnt vmcnt(8)" ::: "memory");  // tile kt landed
        } else {
            asm volatile("s_waitcnt vmcnt(0)" ::: "memory");
        }
        __builtin_amdgcn_s_barrier();   // tile kt visible to all waves

        const unsigned short* Kl = &Klds[buf][0];
        const unsigned short* Vl = &Vlds[buf][0];

        // S^T, permuted A-rows; each kf feeds both q-tiles.
        // s[h][0][j]=S[q=wrow+16h+c][k=8g+j(0..3)], s[h][1][j]=[k=8g+4+j]
        f32x4 s[2][2];
        #pragma unroll
        for (int h = 0; h < 2; ++h) {
            s[h][0] = f32x4{0.f, 0.f, 0.f, 0.f};
            s[h][1] = f32x4{0.f, 0.f, 0.f, 0.f};
        }
        __builtin_amdgcn_s_setprio(1);
        #pragma unroll
        for (int ks = 0; ks < 8; ++ks) {
            int off = (ks * 32 + g * 8) ^ xk;
            bf16x8 kf0 = *(const bf16x8*)&Kl[rphi * 256 + off];
            bf16x8 kf1 = *(const bf16x8*)&Kl[(rphi + 4) * 256 + off];
            s[0][0] = __builtin_amdgcn_mfma_f32_16x16x32_bf16(kf0, qf[0][ks], s[0][0], 0, 0, 0);
            s[1][0] = __builtin_amdgcn_mfma_f32_16x16x32_bf16(kf0, qf[1][ks], s[1][0], 0, 0, 0);
            s[0][1] = __builtin_amdgcn_mfma_f32_16x16x32_bf16(kf1, qf[0][ks], s[0][1], 0, 0, 0);
            s[1][1] = __builtin_amdgcn_mfma_f32_16x16x32_bf16(kf1, qf[1][ks], s[1][1], 0, 0, 0);
        }
        __builtin_amdgcn_s_setprio(0);

        // lane-local defer-max softmax per q-tile
        float pm[2];
        #pragma unroll
        for (int h = 0; h < 2; ++h)
            pm[h] = fmaxf(fmaxf(fmaxf(s[h][0][0], s[h][0][1]), fmaxf(s[h][0][2], s[h][0][3])),
                          fmaxf(fmaxf(s[h][1][0], s[h][1][1]), fmaxf(s[h][1][2], s[h][1][3])));
        bool ok = (pm[0] <= m[0] + 8.f) && (pm[1] <= m[1] + 8.f);
        if (!__all(ok)) {
            #pragma unroll
            for (int h = 0; h < 2; ++h) {
                float pr = pm[h];
                pr = fmaxf(pr, __shfl_xor(pr, 16));
                pr = fmaxf(pr, __shfl_xor(pr, 32));   // row max across g-lanes
                float mn = fmaxf(m[h], pr);
                float r  = __expf(m[h] - mn);
                m[h] = mn; llane[h] *= r;
                float r0 = __shfl(r, g * 4 + 0), r1 = __shfl(r, g * 4 + 1);
                float r2 = __shfl(r, g * 4 + 2), r3 = __shfl(r, g * 4 + 3);
                #pragma unroll
                for (int nt = 0; nt < 16; ++nt) {
                    o[h][nt][0] *= r0; o[h][nt][1] *= r1;
                    o[h][nt][2] *= r2; o[h][nt][3] *= r3;
                }
            }
        }
        bf16x8 pa0, pa1;
        {
            float p0 = __expf(s[0][0][0] - m[0]), p1 = __expf(s[0][0][1] - m[0]);
            float p2 = __expf(s[0][0][2] - m[0]), p3 = __expf(s[0][0][3] - m[0]);
            float p4 = __expf(s[0][1][0] - m[0]), p5 = __expf(s[0][1][1] - m[0]);
            float p6 = __expf(s[0][1][2] - m[0]), p7 = __expf(s[0][1][3] - m[0]);
            llane[0] += ((p0 + p1) + (p2 + p3)) + ((p4 + p5) + (p6 + p7));
            pa0[0] = f2bf(p0); pa0[1] = f2bf(p1); pa0[2] = f2bf(p2); pa0[3] = f2bf(p3);
            pa0[4] = f2bf(p4); pa0[5] = f2bf(p5); pa0[6] = f2bf(p6); pa0[7] = f2bf(p7);
        }
        {
            float p0 = __expf(s[1][0][0] - m[1]), p1 = __expf(s[1][0][1] - m[1]);
            float p2 = __expf(s[1][0][2] - m[1]), p3 = __expf(s[1][0][3] - m[1]);
            float p4 = __expf(s[1][1][0] - m[1]), p5 = __expf(s[1][1][1] - m[1]);
            float p6 = __expf(s[1][1][2] - m[1]), p7 = __expf(s[1][1][3] - m[1]);
            llane[1] += ((p0 + p1) + (p2 + p3)) + ((p4 + p5) + (p6 + p7));
            pa1[0] = f2bf(p0); pa1[1] = f2bf(p1); pa1[2] = f2bf(p2); pa1[3] = f2bf(p3);
            pa1[4] = f2bf(p4); pa1[5] = f2bf(p5); pa1[6] = f2bf(p6); pa1[7] = f2bf(p7);
        }

        // PV: each vf feeds both q-tiles
        __builtin_amdgcn_s_setprio(1);
        #pragma unroll
        for (int nt = 0; nt < 16; ++nt) {
            bf16x8 vf = *(const bf16x8*)&Vl[(nt * 16 + c) * 32 + vcol];
            o[0][nt] = __builtin_amdgcn_mfma_f32_16x16x32_bf16(pa0, vf, o[0][nt], 0, 0, 0);
            o[1][nt] = __builtin_amdgcn_mfma_f32_16x16x32_bf16(pa1, vf, o[1][nt], 0, 0, 0);
        }
        __builtin_amdgcn_s_setprio(0);
        buf ^= 1;
    }

    // epilogue per q-tile: reduce l across g-lanes, broadcast, store
    #pragma unroll
    for (int h = 0; h < 2; ++h) {
        float lsum = llane[h];
        lsum += __shfl_xor(lsum, 16);
        lsum += __shfl_xor(lsum, 32);
        float inv = 1.0f / lsum;
        float i0 = __shfl(inv, g * 4 + 0), i1 = __shfl(inv, g * 4 + 1);
        float i2 = __shfl(inv, g * 4 + 2), i3 = __shfl(inv, g * 4 + 3);

        const size_t obase = ((size_t)sidx * BATCH * SEQ + (size_t)b * SEQ + wrow + 16 * h) * DIM;
        for (int nt = 0; nt < 16; ++nt) {
            Opart[obase + (size_t)(g * 4 + 0) * DIM + nt * 16 + c] = o[h][nt][0] * i0;
            Opart[obase + (size_t)(g * 4 + 1) * DIM + nt * 16 + c] = o[h][nt][1] * i1;
            Opart[obase + (size_t)(g * 4 + 2) * DIM + nt * 16 + c] = o[h][nt][2] * i2;
            Opart[obase + (size_t)(g * 4 + 3) * DIM + nt * 16 + c] = o[h][nt][3] * i3;
        }
        if (g == 0) {
            ml[(size_t)sidx * BATCH * SEQ + (size_t)b * SEQ + wrow + 16 * h + c] =
                make_float2(m[h], lsum);
        }
    }
}

// ---------------------------------------------------------------------------
// Combine 4 KV-split partials: O = sum_s w_s * O_s, w_s = l_s exp(m_s - M)/L
// ---------------------------------------------------------------------------
__global__ __launch_bounds__(256) void combine_kernel(
    const float* __restrict__ Opart, const float2* __restrict__ ml,
    float* __restrict__ out)
{
    const int t = threadIdx.x;
    const size_t row = (size_t)blockIdx.x * 4 + (t >> 6);
    const int lane = t & 63;

    float2 e[4];
    float M = -1e30f;
    for (int s = 0; s < 4; ++s) {
        e[s] = ml[(size_t)s * BATCH * SEQ + row];
        M = fmaxf(M, e[s].x);
    }
    float wgt[4], L = 0.f;
    for (int s = 0; s < 4; ++s) { wgt[s] = e[s].y * __expf(e[s].x - M); L += wgt[s]; }
    float invL = 1.0f / L;

    f32x4 acc = f32x4{0.f, 0.f, 0.f, 0.f};
    for (int s = 0; s < 4; ++s) {
        f32x4 v = *(const f32x4*)&Opart[((size_t)s * BATCH * SEQ + row) * DIM + lane * 4];
        float ws = wgt[s] * invL;
        acc[0] += ws * v[0]; acc[1] += ws * v[1];
        acc[2] += ws * v[2]; acc[3] += ws * v[3];
    }
    *(f32x4*)&out[row * DIM + lane * 4] = acc;
}

// ---------------------------------------------------------------------------
extern "C" void kernel_launch(void* const* d_in, const int* in_sizes, int n_in,
                              void* d_out, int out_size, void* d_ws, size_t ws_size,
                              hipStream_t stream) {
    const float* x  = (const float*)d_in[0];
    const float* z  = (const float*)d_in[1];
    const float* Wq = (const float*)d_in[2];
    const float* bq = (const float*)d_in[3];
    const float* Wk = (const float*)d_in[4];
    const float* bk = (const float*)d_in[5];
    const float* Wv = (const float*)d_in[6];
    const float* bv = (const float*)d_in[7];
    float* out = (float*)d_out;

    const size_t TENS = (size_t)BATCH * SEQ * DIM;
    unsigned short* Qb  = (unsigned short*)d_ws;
    unsigned short* Kb  = Qb + TENS;
    unsigned short* Vtb = Kb + TENS;

    const size_t base_bytes = 3 * TENS * sizeof(unsigned short);       // 24 MB
    const size_t need4 = base_bytes + 4 * TENS * sizeof(float)         // 64 MB
                       + 4 * (size_t)BATCH * SEQ * sizeof(float2);
    const int nsplit = (ws_size >= need4) ? 4 : 1;

    proj_kernel<false><<<256, 256, 0, stream>>>(x, Wq, bq, Qb, 0.0625f);
    proj_kernel<false><<<256, 256, 0, stream>>>(z, Wk, bk, Kb, 1.0f);
    proj_kernel<true ><<<256, 256, 0, stream>>>(z, Wv, bv, Vtb, 1.0f);

    if (nsplit == 4) {
        float*  Op  = (float*)((char*)d_ws + base_bytes);
        float2* mlb = (float2*)((char*)d_ws + base_bytes + 4 * TENS * sizeof(float));
        fa2_kernel<<<512, 256, 0, stream>>>(Qb, Kb, Vtb, Op, mlb, 4);
        combine_kernel<<<4096, 256, 0, stream>>>(Op, mlb, out);
    } else {
        float2* mlb = (float2*)((char*)d_ws + base_bytes);
        fa2_kernel<<<128, 256, 0, stream>>>(Qb, Kb, Vtb, out, mlb, 1);
    }
}